// Round 10
// baseline (551.973 us; speedup 1.0000x reference)
//
#include <hip/hip_runtime.h>
#include <hip/hip_bf16.h>

// NettackSurrogate: out = Ahat^2 @ (x @ W), Ahat = D^-1/2 (A_noself + I) D^-1/2
// N=100000, E=3200000, IN=512, OUT=64, fp32 in/out.
//
// dinv factorization: norm_rc = dinv_r*dinv_c; with hs = dinv (.) h:
//   hs1 = dinv^2 (.) (hs0_r + sum_c hs0_c);  out = dinv (.) (hs1_r + sum_c hs1_c)
//
// R13 postmortem: gemm software-pipelining NULL (503 vs 497). Third wrong
// gemm theory in a row; G and P have never been DIRECTLY measured (both
// hide under the ~120us poison fills; only G+2P ~ 310 is known). Two
// opposite splits fit: {G~100,P~105} vs {G~40,P~135}.
//
// R14 = R9-best source + MEASUREMENT: hop2 is a pure function of
// (h1,cnt,ell,dinv) -> running it twice is bit-identical on `out` and adds
// exactly P to dur. P = dur - 497; G = 310 - 2P. Probe has its own name;
// if P > ~118us it surfaces in top-5 with counters (FETCH discriminates
// HBM-miss vs L3-resident gathers). Decision rule pre-committed:
//   dur 592-637 -> P 95-140: props dominate, G near 35us stream floor.
//   dur 545-575 -> P 50-75: G 160-210, gemm is the hidden cost -> attack.
//
// bf16 hidden states: per-edge wave gather = one fully-used 128B line.
// fp32 accumulate; absmax 0.0156 vs thr 7.7e-2. GEMM: bf16 2-term split
// MFMA (3 cross terms), W prepacked into B-frag layout.

#define OUTC 64
#define INC 512
#define ELLW 72
#define RPB 128            // rows per bucket (bucket = row >> 7)
#define NBUCK 782          // ceil(100000/128)
#define PBLK 256           // phase-1 blocks (1024 threads each)
#define CAP 32             // slots per (bucket, block) cell = one 128B line
#define OVFCAP 65536

typedef short bf16x8 __attribute__((ext_vector_type(8)));
typedef float f32x4 __attribute__((ext_vector_type(4)));
typedef int i32x4 __attribute__((ext_vector_type(4)));

static __device__ inline short f2bf(float f) {
    union { __hip_bfloat16 b; short s; } u;
    u.b = __float2bfloat16(f);  // RTNE
    return u.s;
}
static __device__ inline float bf2f(unsigned short s) {
    union { float f; unsigned u; } v;
    v.u = ((unsigned)s) << 16;
    return v.f;
}

// ---------------- build (R9) ----------------

__global__ __launch_bounds__(1024) void bucket_scatter(const int* __restrict__ erow,
                                                       int* __restrict__ cnt_pb,
                                                       unsigned int* __restrict__ buf,
                                                       unsigned long long* __restrict__ ovf,
                                                       int* __restrict__ ovf_cnt,
                                                       int nE, int n) {
    __shared__ int lcnt[NBUCK];
    for (int i = threadIdx.x; i < NBUCK; i += 1024) lcnt[i] = 0;
    __syncthreads();
    const int blk = blockIdx.x;
    const int chunk = nE / PBLK;
    const int e0 = blk * chunk;
    const int e1 = (blk == PBLK - 1) ? nE : e0 + chunk;
    const int q0 = e0 >> 2, q1 = e1 >> 2;
    const i32x4* rows4 = (const i32x4*)erow;
    const i32x4* cols4 = (const i32x4*)(erow + nE);
    for (int q = q0 + (int)threadIdx.x; q < q1; q += 1024) {
        i32x4 r4 = __builtin_nontemporal_load(&rows4[q]);
        i32x4 c4 = __builtin_nontemporal_load(&cols4[q]);
#pragma unroll
        for (int k = 0; k < 4; ++k) {
            int r = r4[k], c = c4[k];
            if (r == c) continue;
            int b = r >> 7;
            int p = atomicAdd(&lcnt[b], 1);
            if (p < CAP) {
                buf[((size_t)b * PBLK + blk) * CAP + p] =
                    ((unsigned int)(r & (RPB - 1)) << 17) | (unsigned int)c;
            } else {
                int qq = atomicAdd(ovf_cnt, 1);
                if (qq < OVFCAP)
                    ovf[qq] = ((unsigned long long)(unsigned)r << 32) | (unsigned)c;
            }
        }
    }
    for (int e = (q1 << 2) + (int)threadIdx.x; e < e1; e += 1024) {
        int r = erow[e], c = erow[nE + e];
        if (r == c) continue;
        int b = r >> 7;
        int p = atomicAdd(&lcnt[b], 1);
        if (p < CAP) {
            buf[((size_t)b * PBLK + blk) * CAP + p] =
                ((unsigned int)(r & (RPB - 1)) << 17) | (unsigned int)c;
        } else {
            int qq = atomicAdd(ovf_cnt, 1);
            if (qq < OVFCAP)
                ovf[qq] = ((unsigned long long)(unsigned)r << 32) | (unsigned)c;
        }
    }
    __syncthreads();
    for (int i = threadIdx.x; i < NBUCK; i += 1024) {
        int v = lcnt[i];
        cnt_pb[(size_t)i * PBLK + blk] = v < CAP ? v : CAP;
    }
}

__global__ __launch_bounds__(256) void ell_from_buckets(const unsigned int* __restrict__ buf,
                                                        const int* __restrict__ cnt_pb,
                                                        const unsigned long long* __restrict__ ovf,
                                                        const int* __restrict__ ovf_cnt,
                                                        int* __restrict__ cnt,
                                                        float* __restrict__ dinv,
                                                        int* __restrict__ ell, int n) {
    __shared__ int segc[PBLK];
    __shared__ int rcnt[RPB];
    __shared__ int slab[RPB * ELLW];
    const int b = blockIdx.x;
    for (int i = threadIdx.x; i < PBLK; i += 256) segc[i] = cnt_pb[(size_t)b * PBLK + i];
    for (int i = threadIdx.x; i < RPB; i += 256) rcnt[i] = 0;
    __syncthreads();
    const unsigned int* bb = buf + (size_t)b * PBLK * CAP;
    const int TOT = PBLK * CAP;
    for (int j = threadIdx.x; j < TOT; j += 256) {
        int s = j >> 5;
        int off = j & (CAP - 1);
        if (off < segc[s]) {
            unsigned int u = bb[j];
            int lr = (int)(u >> 17);
            int c = (int)(u & 0x1FFFFu);
            int p = atomicAdd(&rcnt[lr], 1);
            if (p < ELLW) slab[lr * ELLW + p] = c;
        }
    }
    int m = *ovf_cnt;
    if (m > OVFCAP) m = OVFCAP;
    for (int i = threadIdx.x; i < m; i += 256) {
        unsigned long long e = ovf[i];
        int r = (int)(e >> 32);
        if ((r >> 7) == b) {
            int lr = r & (RPB - 1);
            int p = atomicAdd(&rcnt[lr], 1);
            if (p < ELLW) slab[lr * ELLW + p] = (int)(unsigned)(e & 0xFFFFFFFFu);
        }
    }
    __syncthreads();
    for (int lr = threadIdx.x; lr < RPB; lr += 256) {
        int r = b * RPB + lr;
        if (r < n) {
            int d = rcnt[lr];
            cnt[r] = d;
            dinv[r] = rsqrtf((float)d + 1.0f);
        }
    }
    int* dst = ell + (size_t)b * RPB * ELLW;
    for (int i = threadIdx.x; i < RPB * ELLW; i += 256) dst[i] = slab[i];
}

__global__ __launch_bounds__(256) void prep_w(const float* __restrict__ W,
                                              short* __restrict__ Whp,
                                              short* __restrict__ Wlp) {
    const int tid = blockIdx.x * 256 + threadIdx.x;
    const int lane = tid & 63;
    const int frag = tid >> 6;
    const int kt = frag >> 2;
    const int nt = frag & 3;
    const int col = nt * 16 + (lane & 15);
    const int kb = kt * 32 + (lane >> 4) * 8;
    short h8[8], l8[8];
#pragma unroll
    for (int j = 0; j < 8; ++j) {
        float w = W[(size_t)(kb + j) * OUTC + col];
        short wh = f2bf(w);
        h8[j] = wh;
        l8[j] = f2bf(w - bf2f((unsigned short)wh));
    }
    size_t o = ((size_t)frag * 64 + lane) * 8;
#pragma unroll
    for (int j = 0; j < 8; ++j) { Whp[o + j] = h8[j]; Wlp[o + j] = l8[j]; }
}

// ---------------- gemm (R9 simple) ----------------

__global__ __launch_bounds__(256) void gemm_mfma(const float* __restrict__ x,
                                                 const short* __restrict__ Whp,
                                                 const short* __restrict__ Wlp,
                                                 const float* __restrict__ dinv,
                                                 unsigned short* __restrict__ h, int n) {
    const int lane = threadIdx.x & 63;
    const int wid = __builtin_amdgcn_readfirstlane(threadIdx.x >> 6);
    const int m0 = (blockIdx.x * 4 + wid) * 16;
    if (m0 >= n) return;
    const int quad = lane >> 4;
    const int row = m0 + (lane & 15);

    f32x4 acc[4];
#pragma unroll
    for (int nt = 0; nt < 4; ++nt) acc[nt] = (f32x4){0.f, 0.f, 0.f, 0.f};

    const float* xrow = x + (size_t)row * INC + quad * 8;

    for (int kt = 0; kt < 16; ++kt) {
        float4 a0 = *(const float4*)(xrow + kt * 32);
        float4 a1 = *(const float4*)(xrow + kt * 32 + 4);
        float av[8] = {a0.x, a0.y, a0.z, a0.w, a1.x, a1.y, a1.z, a1.w};
        bf16x8 ah, al;
#pragma unroll
        for (int j = 0; j < 8; ++j) {
            short hj = f2bf(av[j]);
            ah[j] = hj;
            al[j] = f2bf(av[j] - bf2f((unsigned short)hj));
        }
        const size_t fb = ((size_t)kt * 4 * 64 + lane) * 8;
#pragma unroll
        for (int nt = 0; nt < 4; ++nt) {
            bf16x8 bh = *(const bf16x8*)&Whp[fb + (size_t)nt * 64 * 8];
            bf16x8 bl = *(const bf16x8*)&Wlp[fb + (size_t)nt * 64 * 8];
            acc[nt] = __builtin_amdgcn_mfma_f32_16x16x32_bf16(ah, bh, acc[nt], 0, 0, 0);
            acc[nt] = __builtin_amdgcn_mfma_f32_16x16x32_bf16(ah, bl, acc[nt], 0, 0, 0);
            acc[nt] = __builtin_amdgcn_mfma_f32_16x16x32_bf16(al, bh, acc[nt], 0, 0, 0);
        }
    }
    float dv[4];
#pragma unroll
    for (int reg = 0; reg < 4; ++reg) dv[reg] = dinv[m0 + quad * 4 + reg];
#pragma unroll
    for (int nt = 0; nt < 4; ++nt) {
#pragma unroll
        for (int reg = 0; reg < 4; ++reg) {
            int crow = m0 + quad * 4 + reg;
            h[(size_t)crow * OUTC + nt * 16 + (lane & 15)] =
                (unsigned short)f2bf(dv[reg] * acc[nt][reg]);
        }
    }
}

// ---------------- prop (R9) ----------------

static __device__ inline void prop_body(const unsigned short* __restrict__ hs,
                                        void* __restrict__ hout,
                                        const int* __restrict__ cnt,
                                        const int* __restrict__ ell,
                                        const float* __restrict__ dinv,
                                        int n, int finalhop) {
    const int lane = threadIdx.x & 63;
    const int wid = __builtin_amdgcn_readfirstlane(threadIdx.x >> 6);
    const int node = blockIdx.x * 4 + wid;
    if (node >= n) return;
    float acc = bf2f(hs[(size_t)node * OUTC + lane]);
    int deg = cnt[node];
    if (deg > ELLW) deg = ELLW;
    const int* rowp = ell + (size_t)node * ELLW;
    int j = 0;
    for (; j + 16 <= deg; j += 16) {
        int4 c0 = *(const int4*)(rowp + j);
        int4 c1 = *(const int4*)(rowp + j + 4);
        int4 c2 = *(const int4*)(rowp + j + 8);
        int4 c3 = *(const int4*)(rowp + j + 12);
        float t0 = bf2f(hs[(size_t)c0.x * OUTC + lane]);
        float t1 = bf2f(hs[(size_t)c0.y * OUTC + lane]);
        float t2 = bf2f(hs[(size_t)c0.z * OUTC + lane]);
        float t3 = bf2f(hs[(size_t)c0.w * OUTC + lane]);
        float t4 = bf2f(hs[(size_t)c1.x * OUTC + lane]);
        float t5 = bf2f(hs[(size_t)c1.y * OUTC + lane]);
        float t6 = bf2f(hs[(size_t)c1.z * OUTC + lane]);
        float t7 = bf2f(hs[(size_t)c1.w * OUTC + lane]);
        float t8 = bf2f(hs[(size_t)c2.x * OUTC + lane]);
        float t9 = bf2f(hs[(size_t)c2.y * OUTC + lane]);
        float ta = bf2f(hs[(size_t)c2.z * OUTC + lane]);
        float tb = bf2f(hs[(size_t)c2.w * OUTC + lane]);
        float tc = bf2f(hs[(size_t)c3.x * OUTC + lane]);
        float td = bf2f(hs[(size_t)c3.y * OUTC + lane]);
        float te = bf2f(hs[(size_t)c3.z * OUTC + lane]);
        float tf = bf2f(hs[(size_t)c3.w * OUTC + lane]);
        acc += ((t0 + t1) + (t2 + t3)) + ((t4 + t5) + (t6 + t7));
        acc += ((t8 + t9) + (ta + tb)) + ((tc + td) + (te + tf));
    }
    for (; j + 4 <= deg; j += 4) {
        int4 c0 = *(const int4*)(rowp + j);
        float t0 = bf2f(hs[(size_t)c0.x * OUTC + lane]);
        float t1 = bf2f(hs[(size_t)c0.y * OUTC + lane]);
        float t2 = bf2f(hs[(size_t)c0.z * OUTC + lane]);
        float t3 = bf2f(hs[(size_t)c0.w * OUTC + lane]);
        acc += (t0 + t1) + (t2 + t3);
    }
    for (; j < deg; ++j) {
        int cc = rowp[j];
        acc += bf2f(hs[(size_t)cc * OUTC + lane]);
    }
    float di = dinv[node];
    const size_t oi = (size_t)node * OUTC + lane;
    if (finalhop) {
        ((float*)hout)[oi] = di * acc;
    } else {
        ((unsigned short*)hout)[oi] = (unsigned short)f2bf(di * di * acc);
    }
}

__global__ __launch_bounds__(256) void prop_ell(const unsigned short* __restrict__ hs,
                                                void* __restrict__ hout,
                                                const int* __restrict__ cnt,
                                                const int* __restrict__ ell,
                                                const float* __restrict__ dinv,
                                                int n, int finalhop) {
    prop_body(hs, hout, cnt, ell, dinv, n, finalhop);
}

// Identical body, separate name: idempotent duplicate of hop2 for direct
// per-kernel timing via the rocprof top-5 (P = dur_total - 497).
__global__ __launch_bounds__(256) void prop_ell_probe(const unsigned short* __restrict__ hs,
                                                      void* __restrict__ hout,
                                                      const int* __restrict__ cnt,
                                                      const int* __restrict__ ell,
                                                      const float* __restrict__ dinv,
                                                      int n, int finalhop) {
    prop_body(hs, hout, cnt, ell, dinv, n, finalhop);
}

extern "C" void kernel_launch(void* const* d_in, const int* in_sizes, int n_in,
                              void* d_out, int out_size, void* d_ws, size_t ws_size,
                              hipStream_t stream) {
    const int n = out_size / OUTC;       // 100000
    const int nE = in_sizes[0] / 2;      // 3200000
    const int* erow = (const int*)d_in[0];
    const float* x = (const float*)d_in[1];
    const float* W = (const float*)d_in[2];
    float* out = (float*)d_out;

    char* base = (char*)d_ws;
    size_t off = 0;
    auto take = [&](size_t nbytes) -> void* {
        void* p = base + off;
        off += (nbytes + 255) & ~(size_t)255;
        return p;
    };
    int* cnt = (int*)take((size_t)n * 4);
    float* dinv = (float*)take((size_t)n * 4);
    int* ell = (int*)take((size_t)NBUCK * RPB * ELLW * 4);
    short* Whp = (short*)take((size_t)INC * OUTC * 2);
    short* Wlp = (short*)take((size_t)INC * OUTC * 2);
    unsigned short* h0 = (unsigned short*)take((size_t)n * OUTC * 2);
    unsigned short* h1 = (unsigned short*)take((size_t)n * OUTC * 2);
    unsigned int* buf = (unsigned int*)take((size_t)NBUCK * PBLK * CAP * 4);
    int* cnt_pb = (int*)take((size_t)NBUCK * PBLK * 4);
    unsigned long long* ovf = (unsigned long long*)take((size_t)OVFCAP * 8);
    int* ovf_cnt = (int*)take(256);

    (void)hipMemsetAsync(ovf_cnt, 0, 4, stream);

    bucket_scatter<<<PBLK, 1024, 0, stream>>>(erow, cnt_pb, buf, ovf, ovf_cnt, nE, n);
    ell_from_buckets<<<NBUCK, 256, 0, stream>>>(buf, cnt_pb, ovf, ovf_cnt, cnt, dinv, ell, n);
    prep_w<<<16, 256, 0, stream>>>(W, Whp, Wlp);

    const int nwaves = (n + 15) / 16;
    gemm_mfma<<<(nwaves + 3) / 4, 256, 0, stream>>>(x, Whp, Wlp, dinv, h0, n);

    const int pgrid = (n + 3) / 4;
    prop_ell<<<pgrid, 256, 0, stream>>>(h0, (void*)h1, cnt, ell, dinv, n, 0);
    // measurement probe: identical hop2, run twice (bit-identical `out`)
    prop_ell_probe<<<pgrid, 256, 0, stream>>>(h1, (void*)out, cnt, ell, dinv, n, 1);
    prop_ell<<<pgrid, 256, 0, stream>>>(h1, (void*)out, cnt, ell, dinv, n, 1);
}

// Round 11
// 517.295 us; speedup vs baseline: 1.0670x; 1.0670x over previous
//
#include <hip/hip_runtime.h>
#include <hip/hip_bf16.h>

// NettackSurrogate: out = Ahat^2 @ (x @ W), Ahat = D^-1/2 (A_noself + I) D^-1/2
// N=100000, E=3200000, IN=512, OUT=64, fp32 in/out.
//
// dinv factorization: norm_rc = dinv_r*dinv_c; with hs = dinv (.) h:
//   hs1 = dinv^2 (.) (hs0_r + sum_c hs0_c);  out = dinv (.) (hs1_r + sum_c hs1_c)
//
// R14 MEASUREMENT (idempotent hop2 duplicate): P = 552-497 = 55us/hop.
// Re-closing across R7/R9/R13 eras: gemm ~ 215us (4x the next kernel,
// 6.5x its 33us stream floor). The "props ~105" split was wrong; 3 rounds
// of prop-centric reasoning were misdirected. R12 re-read: merged kernel
// 146us INCLUDING scatter => gemm with {8-wave blocks, nt x loads} ran
// ~100-120us — 2x the standalone 4-wave gemm; the win was masked by the
// bundled rescale pass + nt-prop regressions. Mechanism: 8 co-scheduled
// waves read the SAME 128KB W-frag sequence -> L1 hits instead of ~800MB
// aggregate L2 reads; nt x stream stops evicting W from L1/L2.
//
// R15: gemm = 8 waves/block (782 blocks) + nontemporal x loads + fully
// unrolled kt loop; dinv scale kept in-gemm. All else = R9-best.
// dur - 282 = G_new directly (single change).
//
// bf16 hidden states: per-edge wave gather = one fully-used 128B line.
// fp32 accumulate; absmax 0.0156 vs thr 7.7e-2. GEMM: bf16 2-term split
// MFMA (3 cross terms), W prepacked into B-frag layout.

#define OUTC 64
#define INC 512
#define ELLW 72
#define RPB 128            // rows per bucket (bucket = row >> 7)
#define NBUCK 782          // ceil(100000/128)
#define PBLK 256           // phase-1 blocks (1024 threads each)
#define CAP 32             // slots per (bucket, block) cell = one 128B line
#define OVFCAP 65536

typedef short bf16x8 __attribute__((ext_vector_type(8)));
typedef float f32x4 __attribute__((ext_vector_type(4)));
typedef int i32x4 __attribute__((ext_vector_type(4)));

static __device__ inline short f2bf(float f) {
    union { __hip_bfloat16 b; short s; } u;
    u.b = __float2bfloat16(f);  // RTNE
    return u.s;
}
static __device__ inline float bf2f(unsigned short s) {
    union { float f; unsigned u; } v;
    v.u = ((unsigned)s) << 16;
    return v.f;
}

// ---------------- build (R9) ----------------

__global__ __launch_bounds__(1024) void bucket_scatter(const int* __restrict__ erow,
                                                       int* __restrict__ cnt_pb,
                                                       unsigned int* __restrict__ buf,
                                                       unsigned long long* __restrict__ ovf,
                                                       int* __restrict__ ovf_cnt,
                                                       int nE, int n) {
    __shared__ int lcnt[NBUCK];
    for (int i = threadIdx.x; i < NBUCK; i += 1024) lcnt[i] = 0;
    __syncthreads();
    const int blk = blockIdx.x;
    const int chunk = nE / PBLK;
    const int e0 = blk * chunk;
    const int e1 = (blk == PBLK - 1) ? nE : e0 + chunk;
    const int q0 = e0 >> 2, q1 = e1 >> 2;
    const i32x4* rows4 = (const i32x4*)erow;
    const i32x4* cols4 = (const i32x4*)(erow + nE);
    for (int q = q0 + (int)threadIdx.x; q < q1; q += 1024) {
        i32x4 r4 = __builtin_nontemporal_load(&rows4[q]);
        i32x4 c4 = __builtin_nontemporal_load(&cols4[q]);
#pragma unroll
        for (int k = 0; k < 4; ++k) {
            int r = r4[k], c = c4[k];
            if (r == c) continue;
            int b = r >> 7;
            int p = atomicAdd(&lcnt[b], 1);
            if (p < CAP) {
                buf[((size_t)b * PBLK + blk) * CAP + p] =
                    ((unsigned int)(r & (RPB - 1)) << 17) | (unsigned int)c;
            } else {
                int qq = atomicAdd(ovf_cnt, 1);
                if (qq < OVFCAP)
                    ovf[qq] = ((unsigned long long)(unsigned)r << 32) | (unsigned)c;
            }
        }
    }
    for (int e = (q1 << 2) + (int)threadIdx.x; e < e1; e += 1024) {
        int r = erow[e], c = erow[nE + e];
        if (r == c) continue;
        int b = r >> 7;
        int p = atomicAdd(&lcnt[b], 1);
        if (p < CAP) {
            buf[((size_t)b * PBLK + blk) * CAP + p] =
                ((unsigned int)(r & (RPB - 1)) << 17) | (unsigned int)c;
        } else {
            int qq = atomicAdd(ovf_cnt, 1);
            if (qq < OVFCAP)
                ovf[qq] = ((unsigned long long)(unsigned)r << 32) | (unsigned)c;
        }
    }
    __syncthreads();
    for (int i = threadIdx.x; i < NBUCK; i += 1024) {
        int v = lcnt[i];
        cnt_pb[(size_t)i * PBLK + blk] = v < CAP ? v : CAP;
    }
}

__global__ __launch_bounds__(256) void ell_from_buckets(const unsigned int* __restrict__ buf,
                                                        const int* __restrict__ cnt_pb,
                                                        const unsigned long long* __restrict__ ovf,
                                                        const int* __restrict__ ovf_cnt,
                                                        int* __restrict__ cnt,
                                                        float* __restrict__ dinv,
                                                        int* __restrict__ ell, int n) {
    __shared__ int segc[PBLK];
    __shared__ int rcnt[RPB];
    __shared__ int slab[RPB * ELLW];
    const int b = blockIdx.x;
    for (int i = threadIdx.x; i < PBLK; i += 256) segc[i] = cnt_pb[(size_t)b * PBLK + i];
    for (int i = threadIdx.x; i < RPB; i += 256) rcnt[i] = 0;
    __syncthreads();
    const unsigned int* bb = buf + (size_t)b * PBLK * CAP;
    const int TOT = PBLK * CAP;
    for (int j = threadIdx.x; j < TOT; j += 256) {
        int s = j >> 5;
        int off = j & (CAP - 1);
        if (off < segc[s]) {
            unsigned int u = bb[j];
            int lr = (int)(u >> 17);
            int c = (int)(u & 0x1FFFFu);
            int p = atomicAdd(&rcnt[lr], 1);
            if (p < ELLW) slab[lr * ELLW + p] = c;
        }
    }
    int m = *ovf_cnt;
    if (m > OVFCAP) m = OVFCAP;
    for (int i = threadIdx.x; i < m; i += 256) {
        unsigned long long e = ovf[i];
        int r = (int)(e >> 32);
        if ((r >> 7) == b) {
            int lr = r & (RPB - 1);
            int p = atomicAdd(&rcnt[lr], 1);
            if (p < ELLW) slab[lr * ELLW + p] = (int)(unsigned)(e & 0xFFFFFFFFu);
        }
    }
    __syncthreads();
    for (int lr = threadIdx.x; lr < RPB; lr += 256) {
        int r = b * RPB + lr;
        if (r < n) {
            int d = rcnt[lr];
            cnt[r] = d;
            dinv[r] = rsqrtf((float)d + 1.0f);
        }
    }
    int* dst = ell + (size_t)b * RPB * ELLW;
    for (int i = threadIdx.x; i < RPB * ELLW; i += 256) dst[i] = slab[i];
}

__global__ __launch_bounds__(256) void prep_w(const float* __restrict__ W,
                                              short* __restrict__ Whp,
                                              short* __restrict__ Wlp) {
    const int tid = blockIdx.x * 256 + threadIdx.x;
    const int lane = tid & 63;
    const int frag = tid >> 6;
    const int kt = frag >> 2;
    const int nt = frag & 3;
    const int col = nt * 16 + (lane & 15);
    const int kb = kt * 32 + (lane >> 4) * 8;
    short h8[8], l8[8];
#pragma unroll
    for (int j = 0; j < 8; ++j) {
        float w = W[(size_t)(kb + j) * OUTC + col];
        short wh = f2bf(w);
        h8[j] = wh;
        l8[j] = f2bf(w - bf2f((unsigned short)wh));
    }
    size_t o = ((size_t)frag * 64 + lane) * 8;
#pragma unroll
    for (int j = 0; j < 8; ++j) { Whp[o + j] = h8[j]; Wlp[o + j] = l8[j]; }
}

// ---------------- gemm: 8 waves/block + nt x loads + full unroll ----------------
// 8 waves co-scheduled on one CU read the SAME W-frag sequence -> W stays
// L1-hot (was ~800MB aggregate L2 reads at 4 waves/block). x is read once,
// nontemporal -> doesn't evict W from L1/L2.
__global__ __launch_bounds__(512) void gemm_mfma(const float* __restrict__ x,
                                                 const short* __restrict__ Whp,
                                                 const short* __restrict__ Wlp,
                                                 const float* __restrict__ dinv,
                                                 unsigned short* __restrict__ h, int n) {
    const int lane = threadIdx.x & 63;
    const int wid = __builtin_amdgcn_readfirstlane(threadIdx.x >> 6);
    const int m0 = (blockIdx.x * 8 + wid) * 16;
    if (m0 >= n) return;
    const int quad = lane >> 4;
    const int row = m0 + (lane & 15);

    f32x4 acc[4];
#pragma unroll
    for (int nt = 0; nt < 4; ++nt) acc[nt] = (f32x4){0.f, 0.f, 0.f, 0.f};

    const float* xrow = x + (size_t)row * INC + quad * 8;

#pragma unroll
    for (int kt = 0; kt < 16; ++kt) {
        f32x4 a0 = __builtin_nontemporal_load((const f32x4*)(xrow + kt * 32));
        f32x4 a1 = __builtin_nontemporal_load((const f32x4*)(xrow + kt * 32 + 4));
        float av[8] = {a0[0], a0[1], a0[2], a0[3], a1[0], a1[1], a1[2], a1[3]};
        bf16x8 ah, al;
#pragma unroll
        for (int j = 0; j < 8; ++j) {
            short hj = f2bf(av[j]);
            ah[j] = hj;
            al[j] = f2bf(av[j] - bf2f((unsigned short)hj));
        }
        const size_t fb = ((size_t)kt * 4 * 64 + lane) * 8;
#pragma unroll
        for (int nt = 0; nt < 4; ++nt) {
            bf16x8 bh = *(const bf16x8*)&Whp[fb + (size_t)nt * 64 * 8];
            bf16x8 bl = *(const bf16x8*)&Wlp[fb + (size_t)nt * 64 * 8];
            acc[nt] = __builtin_amdgcn_mfma_f32_16x16x32_bf16(ah, bh, acc[nt], 0, 0, 0);
            acc[nt] = __builtin_amdgcn_mfma_f32_16x16x32_bf16(ah, bl, acc[nt], 0, 0, 0);
            acc[nt] = __builtin_amdgcn_mfma_f32_16x16x32_bf16(al, bh, acc[nt], 0, 0, 0);
        }
    }
    // C/D layout: col = lane&15, row = quad*4 + reg
    float dv[4];
#pragma unroll
    for (int reg = 0; reg < 4; ++reg) dv[reg] = dinv[m0 + quad * 4 + reg];
#pragma unroll
    for (int nt = 0; nt < 4; ++nt) {
#pragma unroll
        for (int reg = 0; reg < 4; ++reg) {
            int crow = m0 + quad * 4 + reg;
            h[(size_t)crow * OUTC + nt * 16 + (lane & 15)] =
                (unsigned short)f2bf(dv[reg] * acc[nt][reg]);
        }
    }
}

// ---------------- prop (R9; measured 55us/hop) ----------------

__global__ __launch_bounds__(256) void prop_ell(const unsigned short* __restrict__ hs,
                                                void* __restrict__ hout,
                                                const int* __restrict__ cnt,
                                                const int* __restrict__ ell,
                                                const float* __restrict__ dinv,
                                                int n, int finalhop) {
    const int lane = threadIdx.x & 63;
    const int wid = __builtin_amdgcn_readfirstlane(threadIdx.x >> 6);
    const int node = blockIdx.x * 4 + wid;
    if (node >= n) return;
    float acc = bf2f(hs[(size_t)node * OUTC + lane]);
    int deg = cnt[node];
    if (deg > ELLW) deg = ELLW;
    const int* rowp = ell + (size_t)node * ELLW;
    int j = 0;
    for (; j + 16 <= deg; j += 16) {
        int4 c0 = *(const int4*)(rowp + j);
        int4 c1 = *(const int4*)(rowp + j + 4);
        int4 c2 = *(const int4*)(rowp + j + 8);
        int4 c3 = *(const int4*)(rowp + j + 12);
        float t0 = bf2f(hs[(size_t)c0.x * OUTC + lane]);
        float t1 = bf2f(hs[(size_t)c0.y * OUTC + lane]);
        float t2 = bf2f(hs[(size_t)c0.z * OUTC + lane]);
        float t3 = bf2f(hs[(size_t)c0.w * OUTC + lane]);
        float t4 = bf2f(hs[(size_t)c1.x * OUTC + lane]);
        float t5 = bf2f(hs[(size_t)c1.y * OUTC + lane]);
        float t6 = bf2f(hs[(size_t)c1.z * OUTC + lane]);
        float t7 = bf2f(hs[(size_t)c1.w * OUTC + lane]);
        float t8 = bf2f(hs[(size_t)c2.x * OUTC + lane]);
        float t9 = bf2f(hs[(size_t)c2.y * OUTC + lane]);
        float ta = bf2f(hs[(size_t)c2.z * OUTC + lane]);
        float tb = bf2f(hs[(size_t)c2.w * OUTC + lane]);
        float tc = bf2f(hs[(size_t)c3.x * OUTC + lane]);
        float td = bf2f(hs[(size_t)c3.y * OUTC + lane]);
        float te = bf2f(hs[(size_t)c3.z * OUTC + lane]);
        float tf = bf2f(hs[(size_t)c3.w * OUTC + lane]);
        acc += ((t0 + t1) + (t2 + t3)) + ((t4 + t5) + (t6 + t7));
        acc += ((t8 + t9) + (ta + tb)) + ((tc + td) + (te + tf));
    }
    for (; j + 4 <= deg; j += 4) {
        int4 c0 = *(const int4*)(rowp + j);
        float t0 = bf2f(hs[(size_t)c0.x * OUTC + lane]);
        float t1 = bf2f(hs[(size_t)c0.y * OUTC + lane]);
        float t2 = bf2f(hs[(size_t)c0.z * OUTC + lane]);
        float t3 = bf2f(hs[(size_t)c0.w * OUTC + lane]);
        acc += (t0 + t1) + (t2 + t3);
    }
    for (; j < deg; ++j) {
        int cc = rowp[j];
        acc += bf2f(hs[(size_t)cc * OUTC + lane]);
    }
    float di = dinv[node];
    const size_t oi = (size_t)node * OUTC + lane;
    if (finalhop) {
        ((float*)hout)[oi] = di * acc;
    } else {
        ((unsigned short*)hout)[oi] = (unsigned short)f2bf(di * di * acc);
    }
}

extern "C" void kernel_launch(void* const* d_in, const int* in_sizes, int n_in,
                              void* d_out, int out_size, void* d_ws, size_t ws_size,
                              hipStream_t stream) {
    const int n = out_size / OUTC;       // 100000
    const int nE = in_sizes[0] / 2;      // 3200000
    const int* erow = (const int*)d_in[0];
    const float* x = (const float*)d_in[1];
    const float* W = (const float*)d_in[2];
    float* out = (float*)d_out;

    char* base = (char*)d_ws;
    size_t off = 0;
    auto take = [&](size_t nbytes) -> void* {
        void* p = base + off;
        off += (nbytes + 255) & ~(size_t)255;
        return p;
    };
    int* cnt = (int*)take((size_t)n * 4);
    float* dinv = (float*)take((size_t)n * 4);
    int* ell = (int*)take((size_t)NBUCK * RPB * ELLW * 4);
    short* Whp = (short*)take((size_t)INC * OUTC * 2);
    short* Wlp = (short*)take((size_t)INC * OUTC * 2);
    unsigned short* h0 = (unsigned short*)take((size_t)n * OUTC * 2);
    unsigned short* h1 = (unsigned short*)take((size_t)n * OUTC * 2);
    unsigned int* buf = (unsigned int*)take((size_t)NBUCK * PBLK * CAP * 4);
    int* cnt_pb = (int*)take((size_t)NBUCK * PBLK * 4);
    unsigned long long* ovf = (unsigned long long*)take((size_t)OVFCAP * 8);
    int* ovf_cnt = (int*)take(256);

    (void)hipMemsetAsync(ovf_cnt, 0, 4, stream);

    bucket_scatter<<<PBLK, 1024, 0, stream>>>(erow, cnt_pb, buf, ovf, ovf_cnt, nE, n);
    ell_from_buckets<<<NBUCK, 256, 0, stream>>>(buf, cnt_pb, ovf, ovf_cnt, cnt, dinv, ell, n);
    prep_w<<<16, 256, 0, stream>>>(W, Whp, Wlp);

    const int nwaves = (n + 15) / 16;              // 6250
    gemm_mfma<<<(nwaves + 7) / 8, 512, 0, stream>>>(x, Whp, Wlp, dinv, h0, n);

    const int pgrid = (n + 3) / 4;
    prop_ell<<<pgrid, 256, 0, stream>>>(h0, (void*)h1, cnt, ell, dinv, n, 0);
    prop_ell<<<pgrid, 256, 0, stream>>>(h1, (void*)out, cnt, ell, dinv, n, 1);
}